// Round 4
// baseline (132.832 us; speedup 1.0000x reference)
//
#include <hip/hip_runtime.h>

#define NB    4            // batches
#define NPTS  8192         // N == M
#define QPL   2            // queries per lane
#define QPB   (64 * QPL)   // 128 queries per block
#define WPB   16           // waves per block (1024 threads)
#define UNR   4            // TPairs per inner iteration (4 pairs = 8 targets, 128 B)

typedef float v2f __attribute__((ext_vector_type(2)));
typedef float v4f __attribute__((ext_vector_type(4)));

// Pair-of-targets SoA: (x0,x1),(y0,y1),(z0,z1),(w0,w1), w = 0.5*||p||^2.  32 B.
struct TPair { v2f xx, yy, zz, ww; };

__global__ void pack_pts(const float* __restrict__ a, const float* __restrict__ b,
                         float4* __restrict__ q4a, float4* __restrict__ q4b,
                         TPair* __restrict__ tpa, TPair* __restrict__ tpb) {
    const int npair = NB * NPTS / 2;
    int i = blockIdx.x * blockDim.x + threadIdx.x;   // [0, 2*npair)
    const float* src = a;
    float4* q4 = q4a;  TPair* tp = tpa;
    int p = i;
    if (i >= npair) { src = b; q4 = q4b; tp = tpb; p = i - npair; }

    float x0 = src[6*p+0], y0 = src[6*p+1], z0 = src[6*p+2];
    float x1 = src[6*p+3], y1 = src[6*p+4], z1 = src[6*p+5];
    float w0 = 0.5f * (x0*x0 + y0*y0 + z0*z0);
    float w1 = 0.5f * (x1*x1 + y1*y1 + z1*z1);
    q4[2*p]   = make_float4(x0, y0, z0, w0);
    q4[2*p+1] = make_float4(x1, y1, z1, w1);
    TPair t;
    t.xx = (v2f){x0, x1}; t.yy = (v2f){y0, y1};
    t.zz = (v2f){z0, z1}; t.ww = (v2f){w0, w1};
    tp[p] = t;
}

// Uniform-address vector load: saddr = SGPR base, voff = wave-uniform VGPR byte
// offset. 64 lanes coalesce to one L1 request; result broadcast to VGPRs.
#define GLD(DST, OFF) \
    asm volatile("global_load_dwordx4 %0, %1, %2 offset:" OFF \
                 : "=v"(DST) : "v"(voff), "s"(Tb))

// e[0:1] = w - q.t for two targets (packed); acc = min3(acc, e0, e1).
// First inst volatile so it cannot be hoisted above the vmcnt wait (rule #18).
#define GROUPV(NQX, NQY, NQZ, TL, TH, ACC) do {                                \
    v2f xx_ = __builtin_shufflevector(TL, TL, 0, 1);                           \
    v2f yy_ = __builtin_shufflevector(TL, TL, 2, 3);                           \
    v2f zz_ = __builtin_shufflevector(TH, TH, 0, 1);                           \
    v2f ww_ = __builtin_shufflevector(TH, TH, 2, 3);                           \
    v2f r_;                                                                    \
    asm volatile("v_pk_mul_f32 %0, %1, %2" : "=v"(r_) : "v"(NQX), "v"(xx_));   \
    asm("v_pk_fma_f32 %0, %1, %2, %0" : "+v"(r_) : "v"(NQY), "v"(yy_));        \
    asm("v_pk_fma_f32 %0, %1, %2, %0" : "+v"(r_) : "v"(NQZ), "v"(zz_));        \
    asm("v_pk_add_f32 %0, %0, %1"     : "+v"(r_) : "v"(ww_));                  \
    asm("v_min3_f32 %0, %0, %1, %2"   : "+v"(ACC) : "v"(r_.x), "v"(r_.y));     \
} while (0)

// Grid: x = NB*(NPTS/QPB), y = dir. Block: 1024 threads = 16 waves.
// Each lane owns two queries (lane, lane+64 of the block's 128-query slab).
// Waves partition the 4096 target-pairs into 256 each; targets stream through
// the VECTOR memory path (uniform-address global_load_dwordx4 -> L1/L2, deep
// MSHRs) instead of the scalar K$, which R3 showed cannot stream (~2000cy/iter
// stalls from MSHR-starved s_load misses).
__launch_bounds__(1024, 8)   // force VGPR <= 64 so 2 blocks/CU (100% occ) fit
__global__ void chamfer_min(const float4* __restrict__ q4a, const float4* __restrict__ q4b,
                            const TPair* __restrict__ tpa, const TPair* __restrict__ tpb,
                            float* __restrict__ accum) {
    __shared__ float red[QPL][WPB][64];

    const int dir = blockIdx.y;
    const int bb  = blockIdx.x / (NPTS / QPB);
    const int blk = blockIdx.x % (NPTS / QPB);

    const float4* __restrict__ Q = (dir == 0 ? q4a : q4b) + bb * NPTS;
    const TPair*  __restrict__ T = (dir == 0 ? tpb : tpa) + bb * (NPTS / 2);

    const int lane = threadIdx.x & 63;
    const int wave = __builtin_amdgcn_readfirstlane((int)(threadIdx.x >> 6));

    const float4 qa = Q[blk * QPB + lane];
    const float4 qb = Q[blk * QPB + 64 + lane];
    v2f nax = (v2f){-qa.x, -qa.x}, nay = (v2f){-qa.y, -qa.y}, naz = (v2f){-qa.z, -qa.z};
    v2f nbx = (v2f){-qb.x, -qb.x}, nby = (v2f){-qb.y, -qb.y}, nbz = (v2f){-qb.z, -qb.z};

    const int PPW = NPTS / 2 / WPB;              // 256 TPairs per wave slice
    const TPair* __restrict__ Tb = T;            // SGPR base for GLD
    unsigned voff = (unsigned)(wave * PPW * sizeof(TPair));   // byte offset, wave-uniform

    float aA0 = 1e30f, aA1 = 1e30f, aB0 = 1e30f, aB1 = 1e30f;

#pragma unroll 1
    for (int it = 0; it < PPW / UNR; ++it) {     // 64 iterations
        v4f t0l, t0h, t1l, t1h, t2l, t2h, t3l, t3h;
        GLD(t0l, "0");  GLD(t0h, "16");
        GLD(t1l, "32"); GLD(t1h, "48");
        GLD(t2l, "64"); GLD(t2h, "80");
        GLD(t3l, "96"); GLD(t3h, "112");
        asm volatile("s_waitcnt vmcnt(0)");
        __builtin_amdgcn_sched_barrier(0);
        GROUPV(nax, nay, naz, t0l, t0h, aA0);
        GROUPV(nbx, nby, nbz, t0l, t0h, aB0);
        GROUPV(nax, nay, naz, t1l, t1h, aA1);
        GROUPV(nbx, nby, nbz, t1l, t1h, aB1);
        GROUPV(nax, nay, naz, t2l, t2h, aA0);
        GROUPV(nbx, nby, nbz, t2l, t2h, aB0);
        GROUPV(nax, nay, naz, t3l, t3h, aA1);
        GROUPV(nbx, nby, nbz, t3l, t3h, aB1);
        voff += UNR * sizeof(TPair);             // +128 B
    }
    float accA = fminf(aA0, aA1);
    float accB = fminf(aB0, aB1);

    red[0][wave][lane] = accA;
    red[1][wave][lane] = accB;
    __syncthreads();

    if (threadIdx.x < 128) {
        const int q = threadIdx.x >> 6;          // 0: qa-row, 1: qb-row
        float v = red[q][0][lane];
#pragma unroll
        for (int w = 1; w < WPB; ++w) v = fminf(v, red[q][w][lane]);
        const float qw = (q == 0) ? qa.w : qb.w;
        float dist = fmaxf(2.0f * (qw + v), 0.0f);
        for (int off = 32; off > 0; off >>= 1)
            dist += __shfl_xor(dist, off, 64);
        if (lane == 0) atomicAdd(&accum[dir], dist);
    }
}

__global__ void finish(const float* __restrict__ accum, float* __restrict__ out) {
    out[0] = (accum[0] + accum[1]) * (1.0f / (NB * NPTS));
}

extern "C" void kernel_launch(void* const* d_in, const int* in_sizes, int n_in,
                              void* d_out, int out_size, void* d_ws, size_t ws_size,
                              hipStream_t stream) {
    const float* in1 = (const float*)d_in[0];
    const float* in2 = (const float*)d_in[1];

    const int tot   = NB * NPTS;      // 32768 points per input
    const int npair = tot / 2;

    char* ws = (char*)d_ws;
    float*  accum = (float*)ws;                      // 2 floats
    float4* q4a   = (float4*)(ws + 256);
    float4* q4b   = q4a + tot;
    TPair*  tpa   = (TPair*)(q4b + tot);
    TPair*  tpb   = tpa + npair;

    hipMemsetAsync(accum, 0, 2 * sizeof(float), stream);

    pack_pts<<<dim3((2 * npair) / 256), 256, 0, stream>>>(in1, in2, q4a, q4b, tpa, tpb);

    dim3 grid(NB * (NPTS / QPB), 2);   // 256 x 2 = 512 blocks, 16 waves each
    chamfer_min<<<grid, 1024, 0, stream>>>(q4a, q4b, tpa, tpb, accum);

    finish<<<1, 1, 0, stream>>>(accum, (float*)d_out);
}

// Round 5
// 81.477 us; speedup vs baseline: 1.6303x; 1.6303x over previous
//
#include <hip/hip_runtime.h>

#define NB    4      // batches
#define NPTS  8192   // N == M
#define QPB2  16     // queries per block (held in VGPRs, negated+duplicated)
#define TPB   256    // threads per block (4 waves)
#define ITERS (NPTS / 2 / TPB)   // 16 TPairs per lane

typedef float v2f __attribute__((ext_vector_type(2)));
typedef float v4f __attribute__((ext_vector_type(4)));

// Target pair SoA: (x0,x1),(y0,y1),(z0,z1),(w0,w1), w = 0.5*||p||^2.  32 B.
struct TPair { v2f xx, yy, zz, ww; };

// Query record: 8 floats {-x,-x, -y,-y, -z,-z, 0.5||q||^2, 0}.  32 B.
__global__ void pack_pts(const float* __restrict__ a, const float* __restrict__ b,
                         TPair* __restrict__ tpa, TPair* __restrict__ tpb,
                         float* __restrict__ nqa, float* __restrict__ nqb) {
    const int npair = NB * NPTS / 2;
    int i = blockIdx.x * blockDim.x + threadIdx.x;   // [0, 2*npair)
    const float* src = a;  TPair* tp = tpa;  float* nq = nqa;
    int p = i;
    if (i >= npair) { src = b; tp = tpb; nq = nqb; p = i - npair; }

    float x0 = src[6*p+0], y0 = src[6*p+1], z0 = src[6*p+2];
    float x1 = src[6*p+3], y1 = src[6*p+4], z1 = src[6*p+5];
    float w0 = 0.5f * (x0*x0 + y0*y0 + z0*z0);
    float w1 = 0.5f * (x1*x1 + y1*y1 + z1*z1);

    TPair t;
    t.xx = (v2f){x0, x1}; t.yy = (v2f){y0, y1};
    t.zz = (v2f){z0, z1}; t.ww = (v2f){w0, w1};
    tp[p] = t;

    v4f* o = (v4f*)(nq + (size_t)2 * p * 8);
    o[0] = (v4f){-x0, -x0, -y0, -y0};
    o[1] = (v4f){-z0, -z0,  w0, 0.f};
    o[2] = (v4f){-x1, -x1, -y1, -y1};
    o[3] = (v4f){-z1, -z1,  w1, 0.f};
}

// e[0:1] = t.w - q.t (2 targets packed) ; acc = min3(acc, e0, e1).
// Query operands qn[] are VGPR-resident (uniform values), targets per-lane VGPRs.
#define GROUPV(J) do {                                                          \
    v2f r_;                                                                     \
    asm("v_pk_mul_f32 %0, %1, %2"     : "=v"(r_) : "v"(qn[3*(J)+0]), "v"(xx_)); \
    asm("v_pk_fma_f32 %0, %1, %2, %0" : "+v"(r_) : "v"(qn[3*(J)+1]), "v"(yy_)); \
    asm("v_pk_fma_f32 %0, %1, %2, %0" : "+v"(r_) : "v"(qn[3*(J)+2]), "v"(zz_)); \
    asm("v_pk_add_f32 %0, %0, %1"     : "+v"(r_) : "v"(ww_));                   \
    asm("v_min3_f32 %0, %0, %1, %2"   : "+v"(acc[J]) : "v"(r_.x), "v"(r_.y));   \
} while (0)

// Grid: (NPTS/QPB2, NB, 2). Block: 256 threads = 4 waves.
// Block owns 16 queries (VGPR-resident); its 256 lanes stream ALL 4096 target
// TPairs per-lane through the vector path (coalesced dwordx4, L2-resident).
// Per-query min completes in-block: shuffle butterfly + 4x16 LDS + 1 atomic.
__launch_bounds__(TPB, 3)
__global__ void chamfer_min(const TPair* __restrict__ tpa, const TPair* __restrict__ tpb,
                            const float* __restrict__ nqa, const float* __restrict__ nqb,
                            float* __restrict__ accum) {
    __shared__ float red[4][QPB2];

    const int qblk = blockIdx.x;
    const int bb   = blockIdx.y;
    const int dir  = blockIdx.z;

    const TPair* __restrict__ T  = (dir == 0 ? tpb : tpa) + bb * (NPTS / 2);
    const float* __restrict__ NQ = (dir == 0 ? nqa : nqb) + ((size_t)bb * NPTS + qblk * QPB2) * 8;

    // Load the block's 16 queries: 6 floats each (negated, duplicated), once.
    v2f qn[3 * QPB2];
#pragma unroll
    for (int i = 0; i < 3 * QPB2; ++i) {
        int q = i / 3, c = i % 3;
        qn[i] = *(const v2f*)(NQ + q * 8 + c * 2);
    }

    float acc[QPB2];
#pragma unroll
    for (int j = 0; j < QPB2; ++j) acc[j] = 1e30f;

    const v4f* __restrict__ T4 = (const v4f*)T;
    const int i0 = threadIdx.x;
    v4f tl = T4[2 * i0], th = T4[2 * i0 + 1];

#pragma unroll 1
    for (int it = 0; it < ITERS; ++it) {
        // prefetch next TPair (wrap on last iter; harmless L2-hot re-read)
        int ni = (i0 + (it + 1) * TPB) & (NPTS / 2 - 1);
        v4f ntl = T4[2 * ni], nth = T4[2 * ni + 1];

        v2f xx_ = __builtin_shufflevector(tl, tl, 0, 1);
        v2f yy_ = __builtin_shufflevector(tl, tl, 2, 3);
        v2f zz_ = __builtin_shufflevector(th, th, 0, 1);
        v2f ww_ = __builtin_shufflevector(th, th, 2, 3);
#pragma unroll
        for (int j = 0; j < QPB2; ++j) GROUPV(j);

        tl = ntl; th = nth;
    }

    // cross-lane min per query (butterfly -> all lanes hold the wave min)
#pragma unroll
    for (int j = 0; j < QPB2; ++j) {
        acc[j] = fminf(acc[j], __shfl_xor(acc[j], 32));
        acc[j] = fminf(acc[j], __shfl_xor(acc[j], 16));
        acc[j] = fminf(acc[j], __shfl_xor(acc[j], 8));
        acc[j] = fminf(acc[j], __shfl_xor(acc[j], 4));
        acc[j] = fminf(acc[j], __shfl_xor(acc[j], 2));
        acc[j] = fminf(acc[j], __shfl_xor(acc[j], 1));
    }

    const int lane = threadIdx.x & 63;
    const int wave = threadIdx.x >> 6;
    if (lane == 0) {
#pragma unroll
        for (int j = 0; j < QPB2; ++j) red[wave][j] = acc[j];
    }
    __syncthreads();

    if (threadIdx.x < QPB2) {
        const int j = threadIdx.x;
        float v = fminf(fminf(red[0][j], red[1][j]), fminf(red[2][j], red[3][j]));
        float q2h = NQ[j * 8 + 6];
        float dist = fmaxf(2.0f * (q2h + v), 0.0f);
        dist += __shfl_xor(dist, 8, 16);
        dist += __shfl_xor(dist, 4, 16);
        dist += __shfl_xor(dist, 2, 16);
        dist += __shfl_xor(dist, 1, 16);
        if (j == 0) atomicAdd(&accum[dir], dist);
    }
}

__global__ void finish(const float* __restrict__ accum, float* __restrict__ out) {
    out[0] = (accum[0] + accum[1]) * (1.0f / (NB * NPTS));
}

extern "C" void kernel_launch(void* const* d_in, const int* in_sizes, int n_in,
                              void* d_out, int out_size, void* d_ws, size_t ws_size,
                              hipStream_t stream) {
    const float* in1 = (const float*)d_in[0];
    const float* in2 = (const float*)d_in[1];

    const int tot   = NB * NPTS;      // 32768 points per input
    const int npair = tot / 2;

    char* ws = (char*)d_ws;
    float*  accum = (float*)ws;                       // 2 floats
    TPair*  tpa   = (TPair*)(ws + 256);               // 512 KB
    TPair*  tpb   = tpa + npair;                      // 512 KB
    float*  nqa   = (float*)(tpb + npair);            // 1 MB (tot * 32 B)
    float*  nqb   = nqa + (size_t)tot * 8;            // 1 MB

    hipMemsetAsync(accum, 0, 2 * sizeof(float), stream);

    pack_pts<<<dim3((2 * npair) / 256), 256, 0, stream>>>(in1, in2, tpa, tpb, nqa, nqb);

    dim3 grid(NPTS / QPB2, NB, 2);    // 512 x 4 x 2 = 4096 blocks
    chamfer_min<<<grid, TPB, 0, stream>>>(tpa, tpb, nqa, nqb, accum);

    finish<<<1, 1, 0, stream>>>(accum, (float*)d_out);
}

// Round 6
// 79.781 us; speedup vs baseline: 1.6649x; 1.0212x over previous
//
#include <hip/hip_runtime.h>

#define NB    4      // batches
#define NPTS  8192   // N == M
#define QPB2  16     // queries per block (VGPR-resident, via op_sel broadcast)
#define TPB   256    // threads per block (4 waves)
#define ITERS (NPTS / 2 / TPB)   // 16 TPairs per lane

typedef float v2f __attribute__((ext_vector_type(2)));
typedef float v4f __attribute__((ext_vector_type(4)));

// Target pair SoA: (x0,x1),(y0,y1),(z0,z1),(w0,w1), w = 0.5*||p||^2.  32 B.
struct TPair { v2f xx, yy, zz, ww; };

// Query record: v4f {-x, -y, -z, 0.5||q||^2}.  16 B.
__global__ void pack_pts(const float* __restrict__ a, const float* __restrict__ b,
                         TPair* __restrict__ tpa, TPair* __restrict__ tpb,
                         v4f* __restrict__ nqa, v4f* __restrict__ nqb) {
    const int npair = NB * NPTS / 2;
    int i = blockIdx.x * blockDim.x + threadIdx.x;   // [0, 2*npair)
    const float* src = a;  TPair* tp = tpa;  v4f* nq = nqa;
    int p = i;
    if (i >= npair) { src = b; tp = tpb; nq = nqb; p = i - npair; }

    float x0 = src[6*p+0], y0 = src[6*p+1], z0 = src[6*p+2];
    float x1 = src[6*p+3], y1 = src[6*p+4], z1 = src[6*p+5];
    float w0 = 0.5f * (x0*x0 + y0*y0 + z0*z0);
    float w1 = 0.5f * (x1*x1 + y1*y1 + z1*z1);

    TPair t;
    t.xx = (v2f){x0, x1}; t.yy = (v2f){y0, y1};
    t.zz = (v2f){z0, z1}; t.ww = (v2f){w0, w1};
    tp[p] = t;

    nq[2*p]   = (v4f){-x0, -y0, -z0, w0};
    nq[2*p+1] = (v4f){-x1, -y1, -z1, w1};
}

// e[0:1] = t.w - q.t for 2 targets, 4 insts via op_sel scalar-broadcast:
//   r = fma(xx, bc(q01.lo), ww) ; r = fma(yy, bc(q01.hi), r) ;
//   r = fma(zz, bc(q23.lo), r)  ; acc = min3(acc, r.lo, r.hi)
// q01 = (-qx,-qy), q23 = (-qz, qw): 4 VGPRs/query, no duplication, no s->v movs.
#define GROUPV(Q01, Q23, ACC) do {                                             \
    v2f r_;                                                                    \
    asm("v_pk_fma_f32 %0, %1, %2, %3 op_sel:[0,0,0] op_sel_hi:[1,0,1]"         \
        : "=v"(r_) : "v"(xx_), "v"(Q01), "v"(ww_));                            \
    asm("v_pk_fma_f32 %0, %1, %2, %0 op_sel:[0,1,0] op_sel_hi:[1,1,1]"         \
        : "+v"(r_) : "v"(yy_), "v"(Q01));                                      \
    asm("v_pk_fma_f32 %0, %1, %2, %0 op_sel:[0,0,0] op_sel_hi:[1,0,1]"         \
        : "+v"(r_) : "v"(zz_), "v"(Q23));                                      \
    asm("v_min3_f32 %0, %0, %1, %2" : "+v"(ACC) : "v"(r_.x), "v"(r_.y));       \
} while (0)

// Grid: (NPTS/QPB2, NB, 2). Block: 256 threads = 4 waves.
// Block owns 16 queries in VGPRs; lanes stream all 4096 target TPairs per-lane
// (coalesced dwordx4, L2-resident) with 1-deep prefetch.
__launch_bounds__(TPB, 4)   // VGPR cap 128 -> 4 waves/SIMD
__global__ void chamfer_min(const TPair* __restrict__ tpa, const TPair* __restrict__ tpb,
                            const v4f* __restrict__ nqa, const v4f* __restrict__ nqb,
                            float* __restrict__ accum) {
    __shared__ float red[4][QPB2];

    const int qblk = blockIdx.x;
    const int bb   = blockIdx.y;
    const int dir  = blockIdx.z;

    const TPair* __restrict__ T   = (dir == 0 ? tpb : tpa) + bb * (NPTS / 2);
    const v4f*   __restrict__ NQ4 = (dir == 0 ? nqa : nqb) + (size_t)bb * NPTS + qblk * QPB2;

    // Load 16 queries; pin into VGPRs once (prevents per-iter s->v copies).
    v2f q01[QPB2], q23[QPB2];
#pragma unroll
    for (int j = 0; j < QPB2; ++j) {
        v4f q = NQ4[j];
        q01[j] = (v2f){q.x, q.y};
        q23[j] = (v2f){q.z, q.w};
        asm("" : "+v"(q01[j]), "+v"(q23[j]));
    }

    float acc[QPB2];
#pragma unroll
    for (int j = 0; j < QPB2; ++j) acc[j] = 1e30f;

    const v4f* __restrict__ T4 = (const v4f*)T;
    unsigned idx = threadIdx.x;                     // TPair index in slice
    v4f tl = T4[2 * idx], th = T4[2 * idx + 1];

#pragma unroll 1
    for (int it = 0; it < ITERS; ++it) {
        unsigned nidx = (idx + TPB) & (NPTS / 2 - 1);   // wrap: harmless hot re-read
        v4f ntl = T4[2 * nidx], nth = T4[2 * nidx + 1];

        v2f xx_ = __builtin_shufflevector(tl, tl, 0, 1);
        v2f yy_ = __builtin_shufflevector(tl, tl, 2, 3);
        v2f zz_ = __builtin_shufflevector(th, th, 0, 1);
        v2f ww_ = __builtin_shufflevector(th, th, 2, 3);
#pragma unroll
        for (int j = 0; j < QPB2; ++j) GROUPV(q01[j], q23[j], acc[j]);

        tl = ntl; th = nth; idx = nidx;
    }

    // cross-lane min per query
#pragma unroll
    for (int j = 0; j < QPB2; ++j) {
        acc[j] = fminf(acc[j], __shfl_xor(acc[j], 32));
        acc[j] = fminf(acc[j], __shfl_xor(acc[j], 16));
        acc[j] = fminf(acc[j], __shfl_xor(acc[j], 8));
        acc[j] = fminf(acc[j], __shfl_xor(acc[j], 4));
        acc[j] = fminf(acc[j], __shfl_xor(acc[j], 2));
        acc[j] = fminf(acc[j], __shfl_xor(acc[j], 1));
    }

    const int lane = threadIdx.x & 63;
    const int wave = threadIdx.x >> 6;
    if (lane == 0) {
#pragma unroll
        for (int j = 0; j < QPB2; ++j) red[wave][j] = acc[j];   // static j only
    }
    __syncthreads();

    if (threadIdx.x < QPB2) {
        const int j = threadIdx.x;
        float v = fminf(fminf(red[0][j], red[1][j]), fminf(red[2][j], red[3][j]));
        float q2h = NQ4[j].w;                       // tiny L2-hot reload (avoids
        float dist = fmaxf(2.0f * (q2h + v), 0.0f); // runtime-indexed reg array)
        dist += __shfl_xor(dist, 8, 16);
        dist += __shfl_xor(dist, 4, 16);
        dist += __shfl_xor(dist, 2, 16);
        dist += __shfl_xor(dist, 1, 16);
        if (j == 0) atomicAdd(&accum[dir], dist);
    }
}

__global__ void finish(const float* __restrict__ accum, float* __restrict__ out) {
    out[0] = (accum[0] + accum[1]) * (1.0f / (NB * NPTS));
}

extern "C" void kernel_launch(void* const* d_in, const int* in_sizes, int n_in,
                              void* d_out, int out_size, void* d_ws, size_t ws_size,
                              hipStream_t stream) {
    const float* in1 = (const float*)d_in[0];
    const float* in2 = (const float*)d_in[1];

    const int tot   = NB * NPTS;      // 32768 points per input
    const int npair = tot / 2;

    char* ws = (char*)d_ws;
    float* accum = (float*)ws;                        // 2 floats
    TPair* tpa   = (TPair*)(ws + 256);                // 512 KB
    TPair* tpb   = tpa + npair;                       // 512 KB
    v4f*   nqa   = (v4f*)(tpb + npair);               // 512 KB
    v4f*   nqb   = nqa + tot;                         // 512 KB

    hipMemsetAsync(accum, 0, 2 * sizeof(float), stream);

    pack_pts<<<dim3((2 * npair) / 256), 256, 0, stream>>>(in1, in2, tpa, tpb, nqa, nqb);

    dim3 grid(NPTS / QPB2, NB, 2);    // 512 x 4 x 2 = 4096 blocks
    chamfer_min<<<grid, TPB, 0, stream>>>(tpa, tpb, nqa, nqb, accum);

    finish<<<1, 1, 0, stream>>>(accum, (float*)d_out);
}

// Round 7
// 77.773 us; speedup vs baseline: 1.7079x; 1.0258x over previous
//
#include <hip/hip_runtime.h>

#define NB     4
#define NPTS   8192
#define NTP    (NPTS / 2)      // 4096 target-pairs per batch
#define TPB    512             // threads per block (8 waves)
#define QPC    32              // queries per chunk (VGPR-resident)
#define NCHUNK 4               // chunks per block -> 128 queries/block
#define SLOTS  64              // blocks per batch (8192 / 128)
#define ITERS  (NTP / TPB)     // 8 target-pair iterations per chunk

typedef float v4f __attribute__((ext_vector_type(4)));

// Monotonic uint key: f1 < f2  <=>  fkey(f1) < fkey(f2) (unsigned), any signs.
__device__ __forceinline__ unsigned fkey(float f) {
    int b = __float_as_int(f);
    return (unsigned)(b ^ ((b >> 31) | 0x80000000));
}
__device__ __forceinline__ float funkey(unsigned k) {
    int b = (k & 0x80000000u) ? (int)(k ^ 0x80000000u) : ~(int)k;
    return __int_as_float(b);
}

// nq[i] = (x, y, z, 0.5||p||^2) per input1 point (queries).
// tp: per input2 target-pair p: tl=(x0,x1,y0,y1), th=(z0,z1,w0,w1).
__global__ void pack_pts(const float* __restrict__ in1, const float* __restrict__ in2,
                         v4f* __restrict__ nq, v4f* __restrict__ tp) {
    int i = blockIdx.x * blockDim.x + threadIdx.x;   // 49152 = 192*256 exact
    if (i < NB * NPTS) {
        float x = in1[3*i], y = in1[3*i+1], z = in1[3*i+2];
        nq[i] = (v4f){x, y, z, 0.5f * (x*x + y*y + z*z)};
    } else {
        int p = i - NB * NPTS;                       // [0, NB*NTP)
        float x0 = in2[6*p+0], y0 = in2[6*p+1], z0 = in2[6*p+2];
        float x1 = in2[6*p+3], y1 = in2[6*p+4], z1 = in2[6*p+5];
        tp[2*p]   = (v4f){x0, x1, y0, y1};
        tp[2*p+1] = (v4f){z0, z1, 0.5f*(x0*x0 + y0*y0 + z0*z0),
                                  0.5f*(x1*x1 + y1*y1 + z1*z1)};
    }
}

// f(q,t) = 0.5||q-t||^2 = qw + tw - q.t  computed ONCE per pair.
// Row (per query) mins live in registers; col (per target) mins accumulate via
// v_min3 into per-iter c0/c1, flushed as uint keys to LDS atomicMin (distinct
// per-lane addresses -> ds_min_u32, no contention). Block covers 128 queries
// (4 chunks x 32) x all 8192 targets of its batch; col partials -> colbuf.
__launch_bounds__(TPB, 1)
__global__ void chamfer_min(const v4f* __restrict__ nq, const v4f* __restrict__ tp,
                            unsigned* __restrict__ colbuf, float* __restrict__ accum) {
    __shared__ unsigned colkey[NPTS];   // [idx]: target 2*idx, [NTP+idx]: 2*idx+1
    __shared__ float red[8][QPC];

    const int slot = blockIdx.x;
    const int bb   = blockIdx.y;
    const int t    = threadIdx.x;
    const int lane = t & 63;
    const int wave = t >> 6;

    uint4 ff = make_uint4(~0u, ~0u, ~0u, ~0u);
#pragma unroll
    for (int k = 0; k < 4; ++k) ((uint4*)colkey)[t + k * TPB] = ff;
    __syncthreads();

    const v4f* __restrict__ Tb = tp + (size_t)bb * (2 * NTP);
    const v4f* __restrict__ Qb = nq + (size_t)bb * NPTS + slot * (NCHUNK * QPC);

    for (int chunk = 0; chunk < NCHUNK; ++chunk) {
        // 32 queries -> VGPRs (pin so the loop body never re-materializes them)
        float qx[QPC], qy[QPC], qz[QPC], qw[QPC];
#pragma unroll
        for (int j = 0; j < QPC; ++j) {
            v4f q = Qb[chunk * QPC + j];
            qx[j] = q.x; qy[j] = q.y; qz[j] = q.z; qw[j] = q.w;
            asm("" : "+v"(qx[j]), "+v"(qy[j]), "+v"(qz[j]), "+v"(qw[j]));
        }

        float accR[QPC];
#pragma unroll
        for (int j = 0; j < QPC; ++j) accR[j] = 1e30f;

        int idx = t;
        v4f tl = Tb[2 * idx], th = Tb[2 * idx + 1];

#pragma unroll 1
        for (int it = 0; it < ITERS; ++it) {
            int nidx = (idx + TPB) & (NTP - 1);          // wrap: hot re-read
            v4f ntl = Tb[2 * nidx], nth = Tb[2 * nidx + 1];

            float x0 = tl.x, x1 = tl.y, y0 = tl.z, y1 = tl.w;
            float z0 = th.x, z1 = th.y, w0 = th.z, w1 = th.w;
            float c0 = 1e30f, c1 = 1e30f;
#pragma unroll
            for (int j = 0; j < QPC; j += 2) {
                float f0 = fmaf(-qx[j],   x0, fmaf(-qy[j],   y0, fmaf(-qz[j],   z0, w0 + qw[j])));
                float f1 = fmaf(-qx[j],   x1, fmaf(-qy[j],   y1, fmaf(-qz[j],   z1, w1 + qw[j])));
                float g0 = fmaf(-qx[j+1], x0, fmaf(-qy[j+1], y0, fmaf(-qz[j+1], z0, w0 + qw[j+1])));
                float g1 = fmaf(-qx[j+1], x1, fmaf(-qy[j+1], y1, fmaf(-qz[j+1], z1, w1 + qw[j+1])));
                asm("v_min3_f32 %0, %0, %1, %2" : "+v"(accR[j])   : "v"(f0), "v"(f1));
                asm("v_min3_f32 %0, %0, %1, %2" : "+v"(accR[j+1]) : "v"(g0), "v"(g1));
                asm("v_min3_f32 %0, %0, %1, %2" : "+v"(c0)        : "v"(f0), "v"(g0));
                asm("v_min3_f32 %0, %0, %1, %2" : "+v"(c1)        : "v"(f1), "v"(g1));
            }
            atomicMin(&colkey[idx],       fkey(c0));
            atomicMin(&colkey[NTP + idx], fkey(c1));
            tl = ntl; th = nth; idx = nidx;
        }

        // row epilogue: wave min -> cross-wave min -> dist sum -> atomicAdd
#pragma unroll
        for (int j = 0; j < QPC; ++j) {
            float a = accR[j];
            a = fminf(a, __shfl_xor(a, 32));
            a = fminf(a, __shfl_xor(a, 16));
            a = fminf(a, __shfl_xor(a, 8));
            a = fminf(a, __shfl_xor(a, 4));
            a = fminf(a, __shfl_xor(a, 2));
            a = fminf(a, __shfl_xor(a, 1));
            accR[j] = a;
        }
        if (lane == 0) {
#pragma unroll
            for (int j = 0; j < QPC; j += 4)
                *(v4f*)&red[wave][j] = (v4f){accR[j], accR[j+1], accR[j+2], accR[j+3]};
        }
        __syncthreads();
        if (t < QPC) {
            float m = red[0][t];
#pragma unroll
            for (int w = 1; w < 8; ++w) m = fminf(m, red[w][t]);
            float dist = fmaxf(2.0f * m, 0.0f);
#pragma unroll
            for (int off = 16; off > 0; off >>= 1)
                dist += __shfl_xor(dist, off, 32);
            if (t == 0) atomicAdd(accum, dist);
        }
        __syncthreads();
    }

    // col partials -> global (plain coalesced stores; combine kernel reduces)
    uint4* cb = (uint4*)(colbuf + (size_t)(bb * SLOTS + slot) * NPTS);
#pragma unroll
    for (int k = 0; k < 4; ++k) cb[t + k * TPB] = ((uint4*)colkey)[t + k * TPB];
}

// Reduce 64 slot-partials per target, sum clamped distances, atomicAdd.
__global__ void col_combine(const unsigned* __restrict__ colbuf, float* __restrict__ accum) {
    int tid = blockIdx.x * blockDim.x + threadIdx.x;   // 8192 threads
    int bb  = tid >> 11;                               // 2048 uint4-threads/batch
    int m4  = tid & 2047;
    const uint4* cb = (const uint4*)(colbuf + (size_t)bb * SLOTS * NPTS);
    uint4 k = make_uint4(~0u, ~0u, ~0u, ~0u);
#pragma unroll 4
    for (int s = 0; s < SLOTS; ++s) {
        uint4 v = cb[s * (NPTS / 4) + m4];
        k.x = min(k.x, v.x); k.y = min(k.y, v.y);
        k.z = min(k.z, v.z); k.w = min(k.w, v.w);
    }
    float dist = fmaxf(2.0f * funkey(k.x), 0.0f) + fmaxf(2.0f * funkey(k.y), 0.0f)
               + fmaxf(2.0f * funkey(k.z), 0.0f) + fmaxf(2.0f * funkey(k.w), 0.0f);
    for (int off = 32; off > 0; off >>= 1) dist += __shfl_xor(dist, off, 64);
    if ((threadIdx.x & 63) == 0) atomicAdd(accum, dist);
}

__global__ void finish(const float* __restrict__ accum, float* __restrict__ out) {
    out[0] = accum[0] * (1.0f / (NB * NPTS));
}

extern "C" void kernel_launch(void* const* d_in, const int* in_sizes, int n_in,
                              void* d_out, int out_size, void* d_ws, size_t ws_size,
                              hipStream_t stream) {
    const float* in1 = (const float*)d_in[0];
    const float* in2 = (const float*)d_in[1];

    char* ws = (char*)d_ws;
    float*    accum  = (float*)ws;                               // 1 float
    v4f*      nq     = (v4f*)(ws + 256);                         // 512 KB
    v4f*      tp     = nq + (size_t)NB * NPTS;                   // 512 KB
    unsigned* colbuf = (unsigned*)(tp + (size_t)NB * NTP * 2);   // 8 MB

    hipMemsetAsync(accum, 0, sizeof(float), stream);

    pack_pts<<<dim3((NB * NPTS + NB * NTP) / 256), 256, 0, stream>>>(in1, in2, nq, tp);

    chamfer_min<<<dim3(SLOTS, NB), TPB, 0, stream>>>(nq, tp, colbuf, accum);

    col_combine<<<dim3(32), 256, 0, stream>>>(colbuf, accum);

    finish<<<1, 1, 0, stream>>>(accum, (float*)d_out);
}

// Round 8
// 74.421 us; speedup vs baseline: 1.7849x; 1.0450x over previous
//
#include <hip/hip_runtime.h>

#define NB     4
#define NPTS   8192
#define NTP    (NPTS / 2)      // 4096 target-pairs per batch
#define TPB    256             // threads per block (4 waves)
#define QPC    16              // queries per chunk (VGPR-resident; 64 regs)
#define ITERS  (NTP / TPB)     // 16 target-pair iterations per chunk

typedef float v4f __attribute__((ext_vector_type(4)));

// nq[i] = (x, y, z, 0.5||p||^2) per input1 point (queries).
// tp: per input2 target-pair p: tl=(x0,x1,y0,y1), th=(z0,z1,w0,w1).
__global__ void pack_pts(const float* __restrict__ in1, const float* __restrict__ in2,
                         v4f* __restrict__ nq, v4f* __restrict__ tp) {
    int i = blockIdx.x * blockDim.x + threadIdx.x;   // 49152 = 192*256 exact
    if (i < NB * NPTS) {
        float x = in1[3*i], y = in1[3*i+1], z = in1[3*i+2];
        nq[i] = (v4f){x, y, z, 0.5f * (x*x + y*y + z*z)};
    } else {
        int p = i - NB * NPTS;                       // [0, NB*NTP)
        float x0 = in2[6*p+0], y0 = in2[6*p+1], z0 = in2[6*p+2];
        float x1 = in2[6*p+3], y1 = in2[6*p+4], z1 = in2[6*p+5];
        tp[2*p]   = (v4f){x0, x1, y0, y1};
        tp[2*p+1] = (v4f){z0, z1, 0.5f*(x0*x0 + y0*y0 + z0*z0),
                                  0.5f*(x1*x1 + y1*y1 + z1*z1)};
    }
}

// f(q,t) = qw + tw - q.t = 0.5||q-t||^2, computed ONCE per pair.
// Row (query) mins in registers; col (target) mins via v_min3 into per-iter
// c0/c1, clamped to 0 (matches reference max(d2,0); makes float bits a
// monotonic uint key) and flushed with LDS ds_min (distinct per-lane addrs).
// SLOTS blocks per batch, each owning NPTS/SLOTS queries x all targets.
template<int SLOTS>
__launch_bounds__(TPB, 4)   // VGPR cap 128: QPC=16 tile sized to fit WITHOUT spill
__global__ void chamfer_min(const v4f* __restrict__ nq, const v4f* __restrict__ tp,
                            unsigned* __restrict__ colbuf, float* __restrict__ accum) {
    constexpr int NCHUNK = (NPTS / SLOTS) / QPC;
    __shared__ unsigned colkey[NPTS];   // [idx]: target 2*idx, [NTP+idx]: 2*idx+1
    __shared__ float red[4][QPC];

    const int slot = blockIdx.x;
    const int bb   = blockIdx.y;
    const int t    = threadIdx.x;
    const int lane = t & 63;
    const int wave = t >> 6;

    uint4 ff = make_uint4(~0u, ~0u, ~0u, ~0u);
#pragma unroll
    for (int k = 0; k < NPTS / 4 / TPB; ++k) ((uint4*)colkey)[t + k * TPB] = ff;
    __syncthreads();

    const v4f* __restrict__ Tb = tp + (size_t)bb * (2 * NTP);
    const v4f* __restrict__ Qb = nq + (size_t)bb * NPTS + slot * (NCHUNK * QPC);

#pragma unroll 1
    for (int chunk = 0; chunk < NCHUNK; ++chunk) {
        // 16 queries -> 64 VGPRs, pinned once (no per-iter re-materialization)
        float qx[QPC], qy[QPC], qz[QPC], qw[QPC];
#pragma unroll
        for (int j = 0; j < QPC; ++j) {
            v4f q = Qb[chunk * QPC + j];
            qx[j] = q.x; qy[j] = q.y; qz[j] = q.z; qw[j] = q.w;
            asm("" : "+v"(qx[j]), "+v"(qy[j]), "+v"(qz[j]), "+v"(qw[j]));
        }

        float accR[QPC];
#pragma unroll
        for (int j = 0; j < QPC; ++j) accR[j] = 1e30f;

        int idx = t;
        v4f tl = Tb[2 * idx], th = Tb[2 * idx + 1];

#pragma unroll 1
        for (int it = 0; it < ITERS; ++it) {
            int nidx = (idx + TPB) & (NTP - 1);          // wrap: hot re-read
            v4f ntl = Tb[2 * nidx], nth = Tb[2 * nidx + 1];

            float x0 = tl.x, x1 = tl.y, y0 = tl.z, y1 = tl.w;
            float z0 = th.x, z1 = th.y, w0 = th.z, w1 = th.w;
            float c0 = 1e30f, c1 = 1e30f;
#pragma unroll
            for (int j = 0; j < QPC; j += 2) {
                float f0 = fmaf(-qx[j],   x0, fmaf(-qy[j],   y0, fmaf(-qz[j],   z0, w0 + qw[j])));
                float f1 = fmaf(-qx[j],   x1, fmaf(-qy[j],   y1, fmaf(-qz[j],   z1, w1 + qw[j])));
                float g0 = fmaf(-qx[j+1], x0, fmaf(-qy[j+1], y0, fmaf(-qz[j+1], z0, w0 + qw[j+1])));
                float g1 = fmaf(-qx[j+1], x1, fmaf(-qy[j+1], y1, fmaf(-qz[j+1], z1, w1 + qw[j+1])));
                asm("v_min3_f32 %0, %0, %1, %2" : "+v"(accR[j])   : "v"(f0), "v"(f1));
                asm("v_min3_f32 %0, %0, %1, %2" : "+v"(accR[j+1]) : "v"(g0), "v"(g1));
                asm("v_min3_f32 %0, %0, %1, %2" : "+v"(c0)        : "v"(f0), "v"(g0));
                asm("v_min3_f32 %0, %0, %1, %2" : "+v"(c1)        : "v"(f1), "v"(g1));
            }
            atomicMin(&colkey[idx],       __float_as_uint(fmaxf(c0, 0.0f)));
            atomicMin(&colkey[NTP + idx], __float_as_uint(fmaxf(c1, 0.0f)));
            tl = ntl; th = nth; idx = nidx;
        }

        // row epilogue: wave min -> cross-wave min -> dist sum -> atomicAdd
#pragma unroll
        for (int j = 0; j < QPC; ++j) {
            float a = accR[j];
            a = fminf(a, __shfl_xor(a, 32));
            a = fminf(a, __shfl_xor(a, 16));
            a = fminf(a, __shfl_xor(a, 8));
            a = fminf(a, __shfl_xor(a, 4));
            a = fminf(a, __shfl_xor(a, 2));
            a = fminf(a, __shfl_xor(a, 1));
            accR[j] = a;
        }
        if (lane == 0) {
#pragma unroll
            for (int j = 0; j < QPC; j += 4)
                *(v4f*)&red[wave][j] = (v4f){accR[j], accR[j+1], accR[j+2], accR[j+3]};
        }
        __syncthreads();
        if (t < QPC) {
            float m = fminf(fminf(red[0][t], red[1][t]), fminf(red[2][t], red[3][t]));
            float dist = fmaxf(2.0f * m, 0.0f);
#pragma unroll
            for (int off = 8; off > 0; off >>= 1)
                dist += __shfl_xor(dist, off, 16);
            if (t == 0) atomicAdd(accum, dist);
        }
        __syncthreads();
    }

    // col partials -> global (plain coalesced stores; combine kernel reduces)
    uint4* cb = (uint4*)(colbuf + (size_t)(bb * SLOTS + slot) * NPTS);
#pragma unroll
    for (int k = 0; k < NPTS / 4 / TPB; ++k) cb[t + k * TPB] = ((uint4*)colkey)[t + k * TPB];
}

// Reduce SLOTS slot-partials per target, sum distances, atomicAdd.
template<int SLOTS>
__global__ void col_combine(const unsigned* __restrict__ colbuf, float* __restrict__ accum) {
    int tid = blockIdx.x * blockDim.x + threadIdx.x;   // 32768 threads
    int bb  = tid >> 13;
    int m   = tid & (NPTS - 1);
    const unsigned* cb = colbuf + (size_t)bb * SLOTS * NPTS + m;
    unsigned k = ~0u;
#pragma unroll 8
    for (int s = 0; s < SLOTS; ++s) k = min(k, cb[(size_t)s * NPTS]);
    float dist = 2.0f * __uint_as_float(k);            // already clamped >= 0
    for (int off = 32; off > 0; off >>= 1) dist += __shfl_xor(dist, off, 64);
    if ((threadIdx.x & 63) == 0) atomicAdd(accum, dist);
}

__global__ void finish(const float* __restrict__ accum, float* __restrict__ out) {
    out[0] = accum[0] * (1.0f / (NB * NPTS));
}

extern "C" void kernel_launch(void* const* d_in, const int* in_sizes, int n_in,
                              void* d_out, int out_size, void* d_ws, size_t ws_size,
                              hipStream_t stream) {
    const float* in1 = (const float*)d_in[0];
    const float* in2 = (const float*)d_in[1];

    char* ws = (char*)d_ws;
    float*    accum  = (float*)ws;                               // 1 float
    v4f*      nq     = (v4f*)(ws + 256);                         // 512 KB
    v4f*      tp     = nq + (size_t)NB * NPTS;                   // 512 KB
    unsigned* colbuf = (unsigned*)(tp + (size_t)NB * NTP * 2);

    hipMemsetAsync(accum, 0, sizeof(float), stream);
    pack_pts<<<dim3((NB * NPTS + NB * NTP) / 256), 256, 0, stream>>>(in1, in2, nq, tp);

    const size_t base = 256 + (size_t)NB * NPTS * 16 * 2;
    const size_t need128 = base + (size_t)128 * NB * NPTS * 4;   // ~17.8 MB

    if (ws_size >= need128) {
        chamfer_min<128><<<dim3(128, NB), TPB, 0, stream>>>(nq, tp, colbuf, accum);
        col_combine<128><<<dim3(128), 256, 0, stream>>>(colbuf, accum);
    } else {
        chamfer_min<64><<<dim3(64, NB), TPB, 0, stream>>>(nq, tp, colbuf, accum);
        col_combine<64><<<dim3(128), 256, 0, stream>>>(colbuf, accum);
    }

    finish<<<1, 1, 0, stream>>>(accum, (float*)d_out);
}